// Round 5
// baseline (18160.873 us; speedup 1.0000x reference)
//
#include <hip/hip_runtime.h>
#include <stdint.h>

#pragma clang fp contract(off)

#define POP 4096
#define DIM 512
#define GENS 50

// ---------------- threefry2x32 (JAX-compatible) ----------------
__host__ __device__ __forceinline__ void tf2x32(uint32_t k0, uint32_t k1,
                                                uint32_t x0, uint32_t x1,
                                                uint32_t &o0, uint32_t &o1) {
  uint32_t ks2 = k0 ^ k1 ^ 0x1BD11BDAu;
#define TFR(r) do { x0 += x1; x1 = (x1 << (r)) | (x1 >> (32 - (r))); x1 ^= x0; } while (0)
  x0 += k0; x1 += k1;
  TFR(13); TFR(15); TFR(26); TFR(6);
  x0 += k1; x1 += ks2 + 1u;
  TFR(17); TFR(29); TFR(16); TFR(24);
  x0 += ks2; x1 += k0 + 2u;
  TFR(13); TFR(15); TFR(26); TFR(6);
  x0 += k0; x1 += k1 + 3u;
  TFR(17); TFR(29); TFR(16); TFR(24);
  x0 += k1; x1 += ks2 + 4u;
  TFR(13); TFR(15); TFR(26); TFR(6);
  x0 += ks2; x1 += k0 + 5u;
#undef TFR
  o0 = x0; o1 = x1;
}

// JAX partitionable threefry (default since jax 0.4.36+):
// random_bits(key, 32, shape)[i] = o0 ^ o1 of threefry2x32(key, (0, i))
__device__ __forceinline__ uint32_t randbits32(uint32_t k0, uint32_t k1, uint32_t e) {
  uint32_t y0, y1;
  tf2x32(k0, k1, 0u, e, y0, y1);
  return y0 ^ y1;
}

__device__ __forceinline__ float u01f(uint32_t bits) {
  return __uint_as_float((bits >> 9) | 0x3F800000u) - 1.0f;
}

// XLA f32 erfinv (Giles) — separate mul+add (no contraction), matching XLA IR
__device__ __forceinline__ float erfinv32(float x) {
  float w = -log1pf(-x * x);
  float p;
  if (w < 5.0f) {
    w = w - 2.5f;
    p = 2.81022636e-08f;
    p = p * w + 3.43273939e-07f;
    p = p * w + -3.5233877e-06f;
    p = p * w + -4.39150654e-06f;
    p = p * w + 0.00021858087f;
    p = p * w + -0.00125372503f;
    p = p * w + -0.00417768164f;
    p = p * w + 0.246640727f;
    p = p * w + 1.50140941f;
  } else {
    w = sqrtf(w) - 3.0f;
    p = -0.000200214257f;
    p = p * w + 0.000100950558f;
    p = p * w + 0.00134934322f;
    p = p * w + -0.00367342844f;
    p = p * w + 0.00573950773f;
    p = p * w + -0.0076224613f;
    p = p * w + 0.00943887047f;
    p = p * w + 1.00167406f;
    p = p * w + 2.83297682f;
  }
  return p * x;
}

// jax.random.normal element: u = f*2.0f + lo (lo = -(1-2^-24)), sqrt2*erfinv
__device__ __forceinline__ float normal_elem(uint32_t k0, uint32_t k1, uint32_t e) {
  float f = u01f(randbits32(k0, k1, e));
  float u = f * 2.0f + (-0.99999994039535522f);
  u = fmaxf(-0.99999994039535522f, u);
  return 1.41421353816986084f * erfinv32(u);  // float(np.sqrt(2))
}

// ---------------- encoder: matvec out[j] = act(bias[j] + dot(W[j,:], x)) ----
__global__ __launch_bounds__(256) void matvec_kernel(
    const float* __restrict__ W, const float* __restrict__ bias,
    const float* __restrict__ x, float* __restrict__ out,
    int N, int K, int act) {
  int j = (blockIdx.x * blockDim.x + threadIdx.x) >> 6;
  int lane = threadIdx.x & 63;
  if (j >= N) return;
  const float* wr = W + (size_t)j * K;
  float acc = 0.0f;
  for (int k = lane; k < K; k += 64) acc = fmaf(wr[k], x[k], acc);
#pragma unroll
  for (int o = 32; o > 0; o >>= 1) acc += __shfl_down(acc, o, 64);
  if (lane == 0) {
    float v = acc + bias[j];
    if (act) v = fmaxf(v, 0.0f);
    out[j] = v;
  }
}

// layernorm in-place: x = LN(x + delta) * w + b
__global__ __launch_bounds__(512) void ln_kernel(
    float* __restrict__ x, const float* __restrict__ delta,
    const float* __restrict__ w, const float* __restrict__ b) {
  __shared__ float s[512];
  int t = threadIdx.x;
  float v = x[t] + delta[t];
  s[t] = v; __syncthreads();
  for (int h = 256; h > 0; h >>= 1) { if (t < h) s[t] += s[t + h]; __syncthreads(); }
  float m = s[0] * (1.0f / 512.0f);
  __syncthreads();
  float d = v - m;
  s[t] = d * d; __syncthreads();
  for (int h = 256; h > 0; h >>= 1) { if (t < h) s[t] += s[t + h]; __syncthreads(); }
  float var = s[0] * (1.0f / 512.0f);
  float o = d / sqrtf(var + 1e-5f) * w[t] + b[t];
  x[t] = o;
}

// ---------------- row softmax stats (max, sum of exp) -----------------------
__global__ __launch_bounds__(256) void rowstats_kernel(const float* __restrict__ in,
                                                       float* __restrict__ rowm,
                                                       float* __restrict__ rowsum) {
  __shared__ float red[4];
  int r = blockIdx.x;
  const float* row = in + (size_t)r * 4096;
  int t = threadIdx.x, lane = t & 63, wid = t >> 6;
  float v[16];
#pragma unroll
  for (int q = 0; q < 4; q++) {
    float4 f = *reinterpret_cast<const float4*>(row + (size_t)(t + 256 * q) * 4);
    v[q * 4 + 0] = f.x; v[q * 4 + 1] = f.y; v[q * 4 + 2] = f.z; v[q * 4 + 3] = f.w;
  }
  float m = v[0];
#pragma unroll
  for (int q = 1; q < 16; q++) m = fmaxf(m, v[q]);
#pragma unroll
  for (int o = 32; o > 0; o >>= 1) m = fmaxf(m, __shfl_xor(m, o, 64));
  if (lane == 0) red[wid] = m;
  __syncthreads();
  float bm = fmaxf(fmaxf(red[0], red[1]), fmaxf(red[2], red[3]));
  __syncthreads();
  float sum = 0.0f;
#pragma unroll
  for (int q = 0; q < 16; q++) sum += expf(v[q] - bm);
#pragma unroll
  for (int o = 32; o > 0; o >>= 1) sum += __shfl_xor(sum, o, 64);
  if (lane == 0) red[wid] = sum;
  __syncthreads();
  if (t == 0) {
    rowm[r] = bm;
    rowsum[r] = (red[0] + red[1]) + (red[2] + red[3]);
  }
}

// ---------------- full softmax materialization (if ws allows) ---------------
__global__ __launch_bounds__(256) void softmax_write_kernel(
    const float* __restrict__ in, const float* __restrict__ rowm,
    const float* __restrict__ rowsum, float* __restrict__ out) {
  int r = blockIdx.x;
  float bm = rowm[r], bs = rowsum[r];
  const float* row = in + (size_t)r * 4096;
  float* orow = out + (size_t)r * 4096;
  int t = threadIdx.x;
#pragma unroll
  for (int q = 0; q < 4; q++) {
    float4 f = *reinterpret_cast<const float4*>(row + (size_t)(t + 256 * q) * 4);
    f.x = expf(f.x - bm) / bs; f.y = expf(f.y - bm) / bs;
    f.z = expf(f.z - bm) / bs; f.w = expf(f.w - bm) / bs;
    *reinterpret_cast<float4*>(orow + (size_t)(t + 256 * q) * 4) = f;
  }
}

// ---------------- pop0 ----------------
__global__ __launch_bounds__(256) void pop0_kernel(float* __restrict__ pop,
                                                   const float* __restrict__ ctx,
                                                   uint32_t k0, uint32_t k1) {
  uint32_t e = blockIdx.x * 256 + threadIdx.x;
  float n = normal_elem(k0, k1, e);
  int c = e & 511u;
  float t = ctx[c] * 0.1f;
  pop[e] = n + t;
}

// ---- ent GEMM: qe = (pop+ctx) + 0.3*(softmax(raw) @ (pop+ctx)) -------------
// ONFLY=1: A element = expf(raw - rowm)/rowsum computed during staging.
template <int ONFLY>
__global__ __launch_bounds__(256) void gemm_ent_kernel(
    const float* __restrict__ A, const float* __restrict__ rowm,
    const float* __restrict__ rowsum, const float* __restrict__ pop,
    const float* __restrict__ ctx, float* __restrict__ qe) {
  __shared__ float As[64][33];
  __shared__ float Bs[32][68];
  const int t = threadIdx.x;
  const int tx = t & 15, ty = t >> 4;
  const int row0 = blockIdx.y * 64, col0 = blockIdx.x * 64;
  const int am0 = t >> 3, akq = t & 7;
  const int bkk = t >> 4, bnq = t & 15;
  float4 cvec = *reinterpret_cast<const float4*>(ctx + col0 + bnq * 4);
  float mr[2], sr[2];
  if (ONFLY) {
#pragma unroll
    for (int s = 0; s < 2; s++) {
      int r = row0 + am0 + s * 32;
      mr[s] = rowm[r]; sr[s] = rowsum[r];
    }
  }
  float acc[4][4] = {{0.f}};
  for (int kt = 0; kt < 4096; kt += 32) {
#pragma unroll
    for (int s = 0; s < 2; s++) {
      int m = am0 + s * 32;
      float4 a4 = *reinterpret_cast<const float4*>(A + (size_t)(row0 + m) * 4096 + kt + akq * 4);
      if (ONFLY) {
        a4.x = expf(a4.x - mr[s]) / sr[s];
        a4.y = expf(a4.y - mr[s]) / sr[s];
        a4.z = expf(a4.z - mr[s]) / sr[s];
        a4.w = expf(a4.w - mr[s]) / sr[s];
      }
      As[m][akq * 4 + 0] = a4.x; As[m][akq * 4 + 1] = a4.y;
      As[m][akq * 4 + 2] = a4.z; As[m][akq * 4 + 3] = a4.w;
    }
#pragma unroll
    for (int s = 0; s < 2; s++) {
      int kk = bkk + s * 16;
      float4 b4 = *reinterpret_cast<const float4*>(pop + (size_t)(kt + kk) * 512 + col0 + bnq * 4);
      b4.x += cvec.x; b4.y += cvec.y; b4.z += cvec.z; b4.w += cvec.w;
      *reinterpret_cast<float4*>(&Bs[kk][bnq * 4]) = b4;
    }
    __syncthreads();
#pragma unroll
    for (int k = 0; k < 32; k++) {
      float4 b = *reinterpret_cast<const float4*>(&Bs[k][tx * 4]);
#pragma unroll
      for (int ii = 0; ii < 4; ii++) {
        float a = As[ty * 4 + ii][k];
        acc[ii][0] = fmaf(a, b.x, acc[ii][0]);
        acc[ii][1] = fmaf(a, b.y, acc[ii][1]);
        acc[ii][2] = fmaf(a, b.z, acc[ii][2]);
        acc[ii][3] = fmaf(a, b.w, acc[ii][3]);
      }
    }
    __syncthreads();
  }
#pragma unroll
  for (int ii = 0; ii < 4; ii++) {
    int r = row0 + ty * 4 + ii;
    float4 p4 = *reinterpret_cast<const float4*>(pop + (size_t)r * 512 + col0 + tx * 4);
    float4 cx = *reinterpret_cast<const float4*>(ctx + col0 + tx * 4);
    float4 o;
    o.x = (p4.x + cx.x) + 0.3f * acc[ii][0];
    o.y = (p4.y + cx.y) + 0.3f * acc[ii][1];
    o.z = (p4.z + cx.z) + 0.3f * acc[ii][2];
    o.w = (p4.w + cx.w) + 0.3f * acc[ii][3];
    *reinterpret_cast<float4*>(qe + (size_t)r * 512 + col0 + tx * 4) = o;
  }
}

// ---------------- fc GEMM: out = act(A @ W.T + bias), W row-major [N][K] ----
template <int ACT>
__global__ __launch_bounds__(256) void gemm_fc_kernel(
    const float* __restrict__ A, const float* __restrict__ W,
    const float* __restrict__ bias, float* __restrict__ out, int N, int K) {
  __shared__ float As[64][33];
  __shared__ float Ws[64][33];
  const int t = threadIdx.x;
  const int tx = t & 15, ty = t >> 4;
  const int row0 = blockIdx.y * 64, col0 = blockIdx.x * 64;
  const int m0 = t >> 3, kq = t & 7;
  float acc[4][4] = {{0.f}};
  for (int kt = 0; kt < K; kt += 32) {
#pragma unroll
    for (int s = 0; s < 2; s++) {
      int m = m0 + s * 32;
      float4 a4 = *reinterpret_cast<const float4*>(A + (size_t)(row0 + m) * K + kt + kq * 4);
      As[m][kq * 4 + 0] = a4.x; As[m][kq * 4 + 1] = a4.y;
      As[m][kq * 4 + 2] = a4.z; As[m][kq * 4 + 3] = a4.w;
      float4 w4 = *reinterpret_cast<const float4*>(W + (size_t)(col0 + m) * K + kt + kq * 4);
      Ws[m][kq * 4 + 0] = w4.x; Ws[m][kq * 4 + 1] = w4.y;
      Ws[m][kq * 4 + 2] = w4.z; Ws[m][kq * 4 + 3] = w4.w;
    }
    __syncthreads();
#pragma unroll
    for (int k = 0; k < 32; k++) {
      float bb0 = Ws[tx * 4 + 0][k], bb1 = Ws[tx * 4 + 1][k];
      float bb2 = Ws[tx * 4 + 2][k], bb3 = Ws[tx * 4 + 3][k];
#pragma unroll
      for (int ii = 0; ii < 4; ii++) {
        float a = As[ty * 4 + ii][k];
        acc[ii][0] = fmaf(a, bb0, acc[ii][0]);
        acc[ii][1] = fmaf(a, bb1, acc[ii][1]);
        acc[ii][2] = fmaf(a, bb2, acc[ii][2]);
        acc[ii][3] = fmaf(a, bb3, acc[ii][3]);
      }
    }
    __syncthreads();
  }
#pragma unroll
  for (int ii = 0; ii < 4; ii++) {
    int r = row0 + ty * 4 + ii;
    float4 o;
    o.x = acc[ii][0] + bias[col0 + tx * 4 + 0];
    o.y = acc[ii][1] + bias[col0 + tx * 4 + 1];
    o.z = acc[ii][2] + bias[col0 + tx * 4 + 2];
    o.w = acc[ii][3] + bias[col0 + tx * 4 + 3];
    if (ACT) { o.x = fmaxf(o.x, 0.f); o.y = fmaxf(o.y, 0.f); o.z = fmaxf(o.z, 0.f); o.w = fmaxf(o.w, 0.f); }
    *reinterpret_cast<float4*>(out + (size_t)r * N + col0 + tx * 4) = o;
  }
}

// ---------------- fitness: sigmoid(h2 @ w3.T + b3) + 0.1*normal --------------
__global__ __launch_bounds__(256) void fit_kernel(
    const float* __restrict__ h2, const float* __restrict__ w3,
    const float* __restrict__ b3, float* __restrict__ fit,
    uint32_t k0, uint32_t k1) {
  int gid = blockIdx.x * 256 + threadIdx.x;
  int m = gid >> 6, lane = gid & 63;
  if (m >= POP) return;
  const float* r = h2 + (size_t)m * 128;
  float acc = fmaf(r[lane], w3[lane], r[lane + 64] * w3[lane + 64]);
#pragma unroll
  for (int o = 32; o > 0; o >>= 1) acc += __shfl_down(acc, o, 64);
  if (lane == 0) {
    float s = 1.0f / (1.0f + expf(-(acc + b3[0])));
    float n = normal_elem(k0, k1, (uint32_t)m);
    float t = 0.1f * n;
    fit[m] = s + t;
  }
}

// ---------------- tournament + categorical selection ------------------------
// randint: k1,k2 = split(key) [foldlike]; idx = random_bits(k2) % 4096
// (multiplier term = (2^16 % 4096)^2 % 4096 = 0, so higher_bits vanish).
__global__ __launch_bounds__(256) void select_kernel(
    const float* __restrict__ fit, int* __restrict__ pidx,
    uint32_t ki0, uint32_t ki1,    // k2 of split(ks[1])
    uint32_t kg0, uint32_t kg1) {  // ks[2] (gumbel)
  int r = blockIdx.x * 256 + threadIdx.x;
  if (r >= POP) return;
  float bestv = 0.f; int bestidx = 0; bool first = true;
#pragma unroll
  for (int t = 0; t < 5; t++) {
    uint32_t i = (uint32_t)(r * 5 + t);
    int idx = (int)(randbits32(ki0, ki1, i) & 4095u);
    float f = u01f(randbits32(kg0, kg1, i));
    float u = (f == 0.0f) ? 1.17549435e-38f : f;  // uniform(tiny, 1)
    float g = -logf(-logf(u));
    float val = g + fit[idx] * 10.0f;
    if (first || val > bestv) { bestv = val; bestidx = idx; first = false; }
  }
  pidx[r] = bestidx;
}

// ---------------- crossover + mutation + tunneling + measurement ------------
__device__ __forceinline__ float mutate_val(
    float v, uint32_t e,
    uint32_t k5a, uint32_t k5b, uint32_t k6a, uint32_t k6b,
    uint32_t k7a, uint32_t k7b, uint32_t k8a, uint32_t k8b,
    uint32_t k9a, uint32_t k9b, int do_meas) {
  float um = u01f(randbits32(k5a, k5b, e));
  if (um < 0.15f) {
    float n = normal_elem(k6a, k6b, e);
    float t = n * 0.1f;
    v = v + t;
  }
  float ut = u01f(randbits32(k7a, k7b, e));
  if (ut < 0.05f) {
    float n = normal_elem(k8a, k8b, e);
    float t = n * 0.5f;
    v = v + t;
  }
  if (do_meas) {
    float n = normal_elem(k9a, k9b, e);
    float t = n * 0.05f;
    v = v + t;
  }
  return v;
}

__global__ __launch_bounds__(256) void offspring_kernel(
    const float* __restrict__ pop, const int* __restrict__ pidx,
    float* __restrict__ out,
    uint32_t k3a, uint32_t k3b, uint32_t k4a, uint32_t k4b,
    uint32_t k5a, uint32_t k5b, uint32_t k6a, uint32_t k6b,
    uint32_t k7a, uint32_t k7b, uint32_t k8a, uint32_t k8b,
    uint32_t k9a, uint32_t k9b, int do_meas) {
  uint32_t tid = blockIdx.x * 256 + threadIdx.x;  // < 1048576 (pair, col)
  uint32_t i = tid >> 9, c = tid & 511u;
  int i1 = pidx[2 * i], i2 = pidx[2 * i + 1];
  float p1 = pop[(size_t)i1 * 512 + c];
  float p2 = pop[(size_t)i2 * 512 + c];
  float ucm = u01f(randbits32(k3a, k3b, tid));
  float uef = u01f(randbits32(k4a, k4b, tid));
  bool cm = ucm < 0.5f;
  float c1 = cm ? p1 : p2;
  float c2 = cm ? p2 : p1;
  float ef = uef * 0.2f;
  float mean = (p1 + p2) * 0.5f;
  float t = ef * mean;
  c1 = c1 + t;
  c2 = c2 + t;
  uint32_t e1 = (2 * i) * 512 + c;
  uint32_t e2 = e1 + 512;
  c1 = mutate_val(c1, e1, k5a, k5b, k6a, k6b, k7a, k7b, k8a, k8b, k9a, k9b, do_meas);
  c2 = mutate_val(c2, e2, k5a, k5b, k6a, k6b, k7a, k7b, k8a, k8b, k9a, k9b, do_meas);
  out[e1] = c1;
  out[e2] = c2;
}

// ---------------- final: best row + max fit + objective weights -------------
__global__ __launch_bounds__(1024) void final_kernel(
    const float* __restrict__ fit, const float* __restrict__ pop,
    const float* __restrict__ objw, float* __restrict__ out) {
  __shared__ float vs[1024];
  __shared__ int isi[1024];
  int t = threadIdx.x;
  float bv = -3.4e38f; int bi = 0x7fffffff;
  for (int i = t; i < POP; i += 1024) {
    float v = fit[i];
    if (v > bv) { bv = v; bi = i; }
  }
  vs[t] = bv; isi[t] = bi; __syncthreads();
  for (int h = 512; h > 0; h >>= 1) {
    if (t < h) {
      float v2 = vs[t + h]; int j2 = isi[t + h];
      if (v2 > vs[t] || (v2 == vs[t] && j2 < isi[t])) { vs[t] = v2; isi[t] = j2; }
    }
    __syncthreads();
  }
  int gbi = isi[0]; float gbv = vs[0];
  if (t < 512) out[t] = pop[(size_t)gbi * 512 + t];
  if (t == 0) out[512] = gbv;
  if (t >= 513 && t < 518) out[t] = objw[t - 513];
}

// ---------------- host orchestration ----------------
extern "C" void kernel_launch(void* const* d_in, const int* in_sizes, int n_in,
                              void* d_out, int out_size, void* d_ws, size_t ws_size,
                              hipStream_t stream) {
  const float* pctx  = (const float*)d_in[0];
  const float* qkvw  = (const float*)d_in[1];
  const float* qkvb  = (const float*)d_in[2];
  const float* outw  = (const float*)d_in[3];
  const float* outb  = (const float*)d_in[4];
  const float* ff1w  = (const float*)d_in[5];
  const float* ff1b  = (const float*)d_in[6];
  const float* ff2w  = (const float*)d_in[7];
  const float* ff2b  = (const float*)d_in[8];
  const float* ln1w  = (const float*)d_in[9];
  const float* ln1b  = (const float*)d_in[10];
  const float* ln2w  = (const float*)d_in[11];
  const float* ln2b  = (const float*)d_in[12];
  const float* fw1   = (const float*)d_in[13];
  const float* fb1   = (const float*)d_in[14];
  const float* fw2   = (const float*)d_in[15];
  const float* fb2   = (const float*)d_in[16];
  const float* fw3   = (const float*)d_in[17];
  const float* fb3   = (const float*)d_in[18];
  const float* entraw= (const float*)d_in[19];
  const float* objw  = (const float*)d_in[20];
  float* out = (float*)d_out;

  // workspace layout (floats)
  float* ws    = (float*)d_ws;
  float* popA  = ws;                    // 2097152
  float* popB  = popA + 2097152;        // 2097152
  float* qe    = popB + 2097152;        // 2097152
  float* h1    = qe + 2097152;          // 1048576
  float* h2    = h1 + 1048576;          // 524288
  float* fitb  = h2 + 524288;           // 4096
  float* encx  = fitb + 4096;           // 512
  float* enct1 = encx + 512;            // 2048
  float* enct2 = enct1 + 2048;          // 512
  float* rowm  = enct2 + 512;           // 4096
  float* rowsum= rowm + 4096;           // 4096
  int*   pidx  = (int*)(rowsum + 4096); // 4096 ints
  float* ent   = (float*)(pidx + 4096); // 16777216 (optional)
  size_t base_floats = (size_t)(2097152 * 3 + 1048576 + 524288 + 4096 + 512 + 2048 + 512 + 4096 + 4096 + 4096);
  size_t need_small = base_floats * 4;
  size_t need_big = (base_floats + 16777216) * 4;
  if (ws_size < need_small) return;  // cannot run; fails loudly
  const bool materialize = (ws_size >= need_big);

  // ---- encoder (S=1: attention output == V) ----
  hipMemcpyAsync(encx, pctx, 512 * sizeof(float), hipMemcpyDeviceToDevice, stream);
  for (int l = 0; l < 6; l++) {
    matvec_kernel<<<128, 256, 0, stream>>>(qkvw + ((size_t)l * 1536 + 1024) * 512,
                                           qkvb + (size_t)l * 1536 + 1024, encx, enct1, 512, 512, 0);
    matvec_kernel<<<128, 256, 0, stream>>>(outw + (size_t)l * 512 * 512,
                                           outb + (size_t)l * 512, enct1, enct2, 512, 512, 0);
    ln_kernel<<<1, 512, 0, stream>>>(encx, enct2, ln1w + l * 512, ln1b + l * 512);
    matvec_kernel<<<512, 256, 0, stream>>>(ff1w + (size_t)l * 2048 * 512,
                                           ff1b + (size_t)l * 2048, encx, enct1, 2048, 512, 1);
    matvec_kernel<<<128, 256, 0, stream>>>(ff2w + (size_t)l * 512 * 2048,
                                           ff2b + (size_t)l * 512, enct1, enct2, 512, 2048, 0);
    ln_kernel<<<1, 512, 0, stream>>>(encx, enct2, ln2w + l * 512, ln2b + l * 512);
  }

  // ---- entanglement softmax stats (+ optional materialization) ----
  rowstats_kernel<<<4096, 256, 0, stream>>>(entraw, rowm, rowsum);
  if (materialize)
    softmax_write_kernel<<<4096, 256, 0, stream>>>(entraw, rowm, rowsum, ent);

  // ---- pop0: normal(fold_in(key(42), 0), (POP,D)) + ctx*0.1 ----
  uint32_t kp0, kp1; tf2x32(0u, 42u, 0u, 0u, kp0, kp1);  // fold_in(key, 0)
  pop0_kernel<<<8192, 256, 0, stream>>>(popA, encx, kp0, kp1);

  // ---- generations ----
  float* cur = popA; float* nxt = popB;
  for (int g = 0; g < GENS; ++g) {
    uint32_t kg0, kg1; tf2x32(0u, 42u, 0u, (uint32_t)(g + 1), kg0, kg1);  // fold_in
    // partitionable (foldlike) split(k, 10): ks[i] = threefry(k, (0, i))
    uint32_t ks[10][2];
    for (int i = 0; i < 10; i++) tf2x32(kg0, kg1, 0u, (uint32_t)i, ks[i][0], ks[i][1]);
    // randint's internal split(ks[1], 2) [foldlike]: k2 = threefry(ks[1], (0, 1))
    uint32_t ki0, ki1; tf2x32(ks[1][0], ks[1][1], 0u, 1u, ki0, ki1);

    if (materialize)
      gemm_ent_kernel<0><<<dim3(8, 64), 256, 0, stream>>>(ent, rowm, rowsum, cur, encx, qe);
    else
      gemm_ent_kernel<1><<<dim3(8, 64), 256, 0, stream>>>(entraw, rowm, rowsum, cur, encx, qe);
    gemm_fc_kernel<1><<<dim3(4, 64), 256, 0, stream>>>(qe, fw1, fb1, h1, 256, 512);
    gemm_fc_kernel<1><<<dim3(2, 64), 256, 0, stream>>>(h1, fw2, fb2, h2, 128, 256);
    fit_kernel<<<1024, 256, 0, stream>>>(h2, fw3, fb3, fitb, ks[0][0], ks[0][1]);
    select_kernel<<<16, 256, 0, stream>>>(fitb, pidx, ki0, ki1, ks[2][0], ks[2][1]);
    offspring_kernel<<<4096, 256, 0, stream>>>(cur, pidx, nxt,
        ks[3][0], ks[3][1], ks[4][0], ks[4][1], ks[5][0], ks[5][1], ks[6][0], ks[6][1],
        ks[7][0], ks[7][1], ks[8][0], ks[8][1], ks[9][0], ks[9][1], (g % 10 == 0) ? 1 : 0);
    float* tswap = cur; cur = nxt; nxt = tswap;
  }

  final_kernel<<<1, 1024, 0, stream>>>(fitb, cur, objw, out);
}

// Round 7
// 17044.989 us; speedup vs baseline: 1.0655x; 1.0655x over previous
//
#include <hip/hip_runtime.h>
#include <stdint.h>

#pragma clang fp contract(off)

#define POP 4096
#define DIM 512
#define GENS 50

// ---------------- threefry2x32 (JAX-compatible) ----------------
__host__ __device__ __forceinline__ void tf2x32(uint32_t k0, uint32_t k1,
                                                uint32_t x0, uint32_t x1,
                                                uint32_t &o0, uint32_t &o1) {
  uint32_t ks2 = k0 ^ k1 ^ 0x1BD11BDAu;
#define TFR(r) do { x0 += x1; x1 = (x1 << (r)) | (x1 >> (32 - (r))); x1 ^= x0; } while (0)
  x0 += k0; x1 += k1;
  TFR(13); TFR(15); TFR(26); TFR(6);
  x0 += k1; x1 += ks2 + 1u;
  TFR(17); TFR(29); TFR(16); TFR(24);
  x0 += ks2; x1 += k0 + 2u;
  TFR(13); TFR(15); TFR(26); TFR(6);
  x0 += k0; x1 += k1 + 3u;
  TFR(17); TFR(29); TFR(16); TFR(24);
  x0 += k1; x1 += ks2 + 4u;
  TFR(13); TFR(15); TFR(26); TFR(6);
  x0 += ks2; x1 += k0 + 5u;
#undef TFR
  o0 = x0; o1 = x1;
}

// JAX partitionable threefry (default in modern JAX):
// random_bits(key, 32, shape)[i] = o0 ^ o1 of threefry2x32(key, (0, i))
__device__ __forceinline__ uint32_t randbits32(uint32_t k0, uint32_t k1, uint32_t e) {
  uint32_t y0, y1;
  tf2x32(k0, k1, 0u, e, y0, y1);
  return y0 ^ y1;
}

__device__ __forceinline__ float u01f(uint32_t bits) {
  return __uint_as_float((bits >> 9) | 0x3F800000u) - 1.0f;
}

// XLA f32 erfinv (Giles) — separate mul+add (no contraction), matching XLA IR
__device__ __forceinline__ float erfinv32(float x) {
  float w = -log1pf(-x * x);
  float p;
  if (w < 5.0f) {
    w = w - 2.5f;
    p = 2.81022636e-08f;
    p = p * w + 3.43273939e-07f;
    p = p * w + -3.5233877e-06f;
    p = p * w + -4.39150654e-06f;
    p = p * w + 0.00021858087f;
    p = p * w + -0.00125372503f;
    p = p * w + -0.00417768164f;
    p = p * w + 0.246640727f;
    p = p * w + 1.50140941f;
  } else {
    w = sqrtf(w) - 3.0f;
    p = -0.000200214257f;
    p = p * w + 0.000100950558f;
    p = p * w + 0.00134934322f;
    p = p * w + -0.00367342844f;
    p = p * w + 0.00573950773f;
    p = p * w + -0.0076224613f;
    p = p * w + 0.00943887047f;
    p = p * w + 1.00167406f;
    p = p * w + 2.83297682f;
  }
  return p * x;
}

// jax.random.normal element: u = f*2.0f + lo (lo = -(1-2^-24)), sqrt2*erfinv
__device__ __forceinline__ float normal_elem(uint32_t k0, uint32_t k1, uint32_t e) {
  float f = u01f(randbits32(k0, k1, e));
  float u = f * 2.0f + (-0.99999994039535522f);
  u = fmaxf(-0.99999994039535522f, u);
  return 1.41421353816986084f * erfinv32(u);  // float(np.sqrt(2))
}

// ---------------- encoder: matvec out[j] = act(bias[j] + dot(W[j,:], x)) ----
__global__ __launch_bounds__(256) void matvec_kernel(
    const float* __restrict__ W, const float* __restrict__ bias,
    const float* __restrict__ x, float* __restrict__ out,
    int N, int K, int act) {
  int j = (blockIdx.x * blockDim.x + threadIdx.x) >> 6;
  int lane = threadIdx.x & 63;
  if (j >= N) return;
  const float* wr = W + (size_t)j * K;
  float acc = 0.0f;
  for (int k = lane; k < K; k += 64) acc = fmaf(wr[k], x[k], acc);
#pragma unroll
  for (int o = 32; o > 0; o >>= 1) acc += __shfl_down(acc, o, 64);
  if (lane == 0) {
    float v = acc + bias[j];
    if (act) v = fmaxf(v, 0.0f);
    out[j] = v;
  }
}

// layernorm in-place: x = LN(x + delta) * w + b
__global__ __launch_bounds__(512) void ln_kernel(
    float* __restrict__ x, const float* __restrict__ delta,
    const float* __restrict__ w, const float* __restrict__ b) {
  __shared__ float s[512];
  int t = threadIdx.x;
  float v = x[t] + delta[t];
  s[t] = v; __syncthreads();
  for (int h = 256; h > 0; h >>= 1) { if (t < h) s[t] += s[t + h]; __syncthreads(); }
  float m = s[0] * (1.0f / 512.0f);
  __syncthreads();
  float d = v - m;
  s[t] = d * d; __syncthreads();
  for (int h = 256; h > 0; h >>= 1) { if (t < h) s[t] += s[t + h]; __syncthreads(); }
  float var = s[0] * (1.0f / 512.0f);
  float o = d / sqrtf(var + 1e-5f) * w[t] + b[t];
  x[t] = o;
}

// ---------------- row softmax stats (max, sum of exp) -----------------------
__global__ __launch_bounds__(256) void rowstats_kernel(const float* __restrict__ in,
                                                       float* __restrict__ rowm,
                                                       float* __restrict__ rowsum) {
  __shared__ float red[4];
  int r = blockIdx.x;
  const float* row = in + (size_t)r * 4096;
  int t = threadIdx.x, lane = t & 63, wid = t >> 6;
  float v[16];
#pragma unroll
  for (int q = 0; q < 4; q++) {
    float4 f = *reinterpret_cast<const float4*>(row + (size_t)(t + 256 * q) * 4);
    v[q * 4 + 0] = f.x; v[q * 4 + 1] = f.y; v[q * 4 + 2] = f.z; v[q * 4 + 3] = f.w;
  }
  float m = v[0];
#pragma unroll
  for (int q = 1; q < 16; q++) m = fmaxf(m, v[q]);
#pragma unroll
  for (int o = 32; o > 0; o >>= 1) m = fmaxf(m, __shfl_xor(m, o, 64));
  if (lane == 0) red[wid] = m;
  __syncthreads();
  float bm = fmaxf(fmaxf(red[0], red[1]), fmaxf(red[2], red[3]));
  __syncthreads();
  float sum = 0.0f;
#pragma unroll
  for (int q = 0; q < 16; q++) sum += expf(v[q] - bm);
#pragma unroll
  for (int o = 32; o > 0; o >>= 1) sum += __shfl_xor(sum, o, 64);
  if (lane == 0) red[wid] = sum;
  __syncthreads();
  if (t == 0) {
    rowm[r] = bm;
    rowsum[r] = (red[0] + red[1]) + (red[2] + red[3]);
  }
}

// ---------------- full softmax materialization (if ws allows) ---------------
__global__ __launch_bounds__(256) void softmax_write_kernel(
    const float* __restrict__ in, const float* __restrict__ rowm,
    const float* __restrict__ rowsum, float* __restrict__ out) {
  int r = blockIdx.x;
  float bm = rowm[r], bs = rowsum[r];
  const float* row = in + (size_t)r * 4096;
  float* orow = out + (size_t)r * 4096;
  int t = threadIdx.x;
#pragma unroll
  for (int q = 0; q < 4; q++) {
    float4 f = *reinterpret_cast<const float4*>(row + (size_t)(t + 256 * q) * 4);
    f.x = expf(f.x - bm) / bs; f.y = expf(f.y - bm) / bs;
    f.z = expf(f.z - bm) / bs; f.w = expf(f.w - bm) / bs;
    *reinterpret_cast<float4*>(orow + (size_t)(t + 256 * q) * 4) = f;
  }
}

// ---------------- pop0 ----------------
__global__ __launch_bounds__(256) void pop0_kernel(float* __restrict__ pop,
                                                   const float* __restrict__ ctx,
                                                   uint32_t k0, uint32_t k1) {
  uint32_t e = blockIdx.x * 256 + threadIdx.x;
  float n = normal_elem(k0, k1, e);
  int c = e & 511u;
  float t = ctx[c] * 0.1f;
  pop[e] = n + t;
}

// ---- ent GEMM: qe = (pop+ctx) + 0.3*(softmax(raw) @ (pop+ctx)) -------------
// A-tile stored TRANSPOSED in LDS so the per-k fragment read is one
// ds_read_b128 (16-way broadcast, conflict-free) instead of 4 scalar reads.
// The fmaf accumulation sequence per output element is IDENTICAL to the
// verified round-5 kernel => bit-identical result.
template <int ONFLY>
__global__ __launch_bounds__(256) void gemm_ent_kernel(
    const float* __restrict__ A, const float* __restrict__ rowm,
    const float* __restrict__ rowsum, const float* __restrict__ pop,
    const float* __restrict__ ctx, float* __restrict__ qe) {
  __shared__ __align__(16) float As[32][68];  // [k][m] transposed, 64 rows + pad
  __shared__ __align__(16) float Bs[32][68];  // [k][n]
  const int t = threadIdx.x;
  const int tx = t & 15, ty = t >> 4;
  const int row0 = blockIdx.y * 64, col0 = blockIdx.x * 64;
  const int am0 = t >> 3, akq = t & 7;
  const int bkk = t >> 4, bnq = t & 15;
  float4 cvec = *reinterpret_cast<const float4*>(ctx + col0 + bnq * 4);
  float mr[2], sr[2];
  if (ONFLY) {
#pragma unroll
    for (int s = 0; s < 2; s++) {
      int r = row0 + am0 + s * 32;
      mr[s] = rowm[r]; sr[s] = rowsum[r];
    }
  }
  float acc[4][4] = {{0.f}};
  for (int kt = 0; kt < 4096; kt += 32) {
#pragma unroll
    for (int s = 0; s < 2; s++) {
      int m = am0 + s * 32;
      float4 a4 = *reinterpret_cast<const float4*>(A + (size_t)(row0 + m) * 4096 + kt + akq * 4);
      if (ONFLY) {
        a4.x = expf(a4.x - mr[s]) / sr[s];
        a4.y = expf(a4.y - mr[s]) / sr[s];
        a4.z = expf(a4.z - mr[s]) / sr[s];
        a4.w = expf(a4.w - mr[s]) / sr[s];
      }
      As[akq * 4 + 0][m] = a4.x; As[akq * 4 + 1][m] = a4.y;
      As[akq * 4 + 2][m] = a4.z; As[akq * 4 + 3][m] = a4.w;
    }
#pragma unroll
    for (int s = 0; s < 2; s++) {
      int kk = bkk + s * 16;
      float4 b4 = *reinterpret_cast<const float4*>(pop + (size_t)(kt + kk) * 512 + col0 + bnq * 4);
      b4.x += cvec.x; b4.y += cvec.y; b4.z += cvec.z; b4.w += cvec.w;
      *reinterpret_cast<float4*>(&Bs[kk][bnq * 4]) = b4;
    }
    __syncthreads();
#pragma unroll
    for (int k = 0; k < 32; k++) {
      float4 a = *reinterpret_cast<const float4*>(&As[k][ty * 4]);
      float4 b = *reinterpret_cast<const float4*>(&Bs[k][tx * 4]);
      acc[0][0] = fmaf(a.x, b.x, acc[0][0]);
      acc[0][1] = fmaf(a.x, b.y, acc[0][1]);
      acc[0][2] = fmaf(a.x, b.z, acc[0][2]);
      acc[0][3] = fmaf(a.x, b.w, acc[0][3]);
      acc[1][0] = fmaf(a.y, b.x, acc[1][0]);
      acc[1][1] = fmaf(a.y, b.y, acc[1][1]);
      acc[1][2] = fmaf(a.y, b.z, acc[1][2]);
      acc[1][3] = fmaf(a.y, b.w, acc[1][3]);
      acc[2][0] = fmaf(a.z, b.x, acc[2][0]);
      acc[2][1] = fmaf(a.z, b.y, acc[2][1]);
      acc[2][2] = fmaf(a.z, b.z, acc[2][2]);
      acc[2][3] = fmaf(a.z, b.w, acc[2][3]);
      acc[3][0] = fmaf(a.w, b.x, acc[3][0]);
      acc[3][1] = fmaf(a.w, b.y, acc[3][1]);
      acc[3][2] = fmaf(a.w, b.z, acc[3][2]);
      acc[3][3] = fmaf(a.w, b.w, acc[3][3]);
    }
    __syncthreads();
  }
#pragma unroll
  for (int ii = 0; ii < 4; ii++) {
    int r = row0 + ty * 4 + ii;
    float4 p4 = *reinterpret_cast<const float4*>(pop + (size_t)r * 512 + col0 + tx * 4);
    float4 cx = *reinterpret_cast<const float4*>(ctx + col0 + tx * 4);
    float4 o;
    o.x = (p4.x + cx.x) + 0.3f * acc[ii][0];
    o.y = (p4.y + cx.y) + 0.3f * acc[ii][1];
    o.z = (p4.z + cx.z) + 0.3f * acc[ii][2];
    o.w = (p4.w + cx.w) + 0.3f * acc[ii][3];
    *reinterpret_cast<float4*>(qe + (size_t)r * 512 + col0 + tx * 4) = o;
  }
}

// ---------------- fc GEMM: out = act(A @ W.T + bias), W row-major [N][K] ----
// Same transposed-LDS treatment for both operands; accumulation order
// unchanged => bit-identical to round-5.
template <int ACT>
__global__ __launch_bounds__(256) void gemm_fc_kernel(
    const float* __restrict__ A, const float* __restrict__ W,
    const float* __restrict__ bias, float* __restrict__ out, int N, int K) {
  __shared__ __align__(16) float As[32][68];  // [k][m]
  __shared__ __align__(16) float Ws[32][68];  // [k][n]
  const int t = threadIdx.x;
  const int tx = t & 15, ty = t >> 4;
  const int row0 = blockIdx.y * 64, col0 = blockIdx.x * 64;
  const int m0 = t >> 3, kq = t & 7;
  float acc[4][4] = {{0.f}};
  for (int kt = 0; kt < K; kt += 32) {
#pragma unroll
    for (int s = 0; s < 2; s++) {
      int m = m0 + s * 32;
      float4 a4 = *reinterpret_cast<const float4*>(A + (size_t)(row0 + m) * K + kt + kq * 4);
      As[kq * 4 + 0][m] = a4.x; As[kq * 4 + 1][m] = a4.y;
      As[kq * 4 + 2][m] = a4.z; As[kq * 4 + 3][m] = a4.w;
      float4 w4 = *reinterpret_cast<const float4*>(W + (size_t)(col0 + m) * K + kt + kq * 4);
      Ws[kq * 4 + 0][m] = w4.x; Ws[kq * 4 + 1][m] = w4.y;
      Ws[kq * 4 + 2][m] = w4.z; Ws[kq * 4 + 3][m] = w4.w;
    }
    __syncthreads();
#pragma unroll
    for (int k = 0; k < 32; k++) {
      float4 a = *reinterpret_cast<const float4*>(&As[k][ty * 4]);
      float4 b = *reinterpret_cast<const float4*>(&Ws[k][tx * 4]);
      acc[0][0] = fmaf(a.x, b.x, acc[0][0]);
      acc[0][1] = fmaf(a.x, b.y, acc[0][1]);
      acc[0][2] = fmaf(a.x, b.z, acc[0][2]);
      acc[0][3] = fmaf(a.x, b.w, acc[0][3]);
      acc[1][0] = fmaf(a.y, b.x, acc[1][0]);
      acc[1][1] = fmaf(a.y, b.y, acc[1][1]);
      acc[1][2] = fmaf(a.y, b.z, acc[1][2]);
      acc[1][3] = fmaf(a.y, b.w, acc[1][3]);
      acc[2][0] = fmaf(a.z, b.x, acc[2][0]);
      acc[2][1] = fmaf(a.z, b.y, acc[2][1]);
      acc[2][2] = fmaf(a.z, b.z, acc[2][2]);
      acc[2][3] = fmaf(a.z, b.w, acc[2][3]);
      acc[3][0] = fmaf(a.w, b.x, acc[3][0]);
      acc[3][1] = fmaf(a.w, b.y, acc[3][1]);
      acc[3][2] = fmaf(a.w, b.z, acc[3][2]);
      acc[3][3] = fmaf(a.w, b.w, acc[3][3]);
    }
    __syncthreads();
  }
#pragma unroll
  for (int ii = 0; ii < 4; ii++) {
    int r = row0 + ty * 4 + ii;
    float4 o;
    o.x = acc[ii][0] + bias[col0 + tx * 4 + 0];
    o.y = acc[ii][1] + bias[col0 + tx * 4 + 1];
    o.z = acc[ii][2] + bias[col0 + tx * 4 + 2];
    o.w = acc[ii][3] + bias[col0 + tx * 4 + 3];
    if (ACT) { o.x = fmaxf(o.x, 0.f); o.y = fmaxf(o.y, 0.f); o.z = fmaxf(o.z, 0.f); o.w = fmaxf(o.w, 0.f); }
    *reinterpret_cast<float4*>(out + (size_t)r * N + col0 + tx * 4) = o;
  }
}

// ---------------- fitness: sigmoid(h2 @ w3.T + b3) + 0.1*normal --------------
__global__ __launch_bounds__(256) void fit_kernel(
    const float* __restrict__ h2, const float* __restrict__ w3,
    const float* __restrict__ b3, float* __restrict__ fit,
    uint32_t k0, uint32_t k1) {
  int gid = blockIdx.x * 256 + threadIdx.x;
  int m = gid >> 6, lane = gid & 63;
  if (m >= POP) return;
  const float* r = h2 + (size_t)m * 128;
  float acc = fmaf(r[lane], w3[lane], r[lane + 64] * w3[lane + 64]);
#pragma unroll
  for (int o = 32; o > 0; o >>= 1) acc += __shfl_down(acc, o, 64);
  if (lane == 0) {
    float s = 1.0f / (1.0f + expf(-(acc + b3[0])));
    float n = normal_elem(k0, k1, (uint32_t)m);
    float t = 0.1f * n;
    fit[m] = s + t;
  }
}

// ---------------- tournament + categorical selection ------------------------
__global__ __launch_bounds__(256) void select_kernel(
    const float* __restrict__ fit, int* __restrict__ pidx,
    uint32_t ki0, uint32_t ki1,    // k2 of split(ks[1])
    uint32_t kg0, uint32_t kg1) {  // ks[2] (gumbel)
  int r = blockIdx.x * 256 + threadIdx.x;
  if (r >= POP) return;
  float bestv = 0.f; int bestidx = 0; bool first = true;
#pragma unroll
  for (int t = 0; t < 5; t++) {
    uint32_t i = (uint32_t)(r * 5 + t);
    int idx = (int)(randbits32(ki0, ki1, i) & 4095u);
    float f = u01f(randbits32(kg0, kg1, i));
    float u = (f == 0.0f) ? 1.17549435e-38f : f;  // uniform(tiny, 1)
    float g = -logf(-logf(u));
    float val = g + fit[idx] * 10.0f;
    if (first || val > bestv) { bestv = val; bestidx = idx; first = false; }
  }
  pidx[r] = bestidx;
}

// ---------------- crossover + mutation + tunneling + measurement ------------
__device__ __forceinline__ float mutate_val(
    float v, uint32_t e,
    uint32_t k5a, uint32_t k5b, uint32_t k6a, uint32_t k6b,
    uint32_t k7a, uint32_t k7b, uint32_t k8a, uint32_t k8b,
    uint32_t k9a, uint32_t k9b, int do_meas) {
  float um = u01f(randbits32(k5a, k5b, e));
  if (um < 0.15f) {
    float n = normal_elem(k6a, k6b, e);
    float t = n * 0.1f;
    v = v + t;
  }
  float ut = u01f(randbits32(k7a, k7b, e));
  if (ut < 0.05f) {
    float n = normal_elem(k8a, k8b, e);
    float t = n * 0.5f;
    v = v + t;
  }
  if (do_meas) {
    float n = normal_elem(k9a, k9b, e);
    float t = n * 0.05f;
    v = v + t;
  }
  return v;
}

__global__ __launch_bounds__(256) void offspring_kernel(
    const float* __restrict__ pop, const int* __restrict__ pidx,
    float* __restrict__ out,
    uint32_t k3a, uint32_t k3b, uint32_t k4a, uint32_t k4b,
    uint32_t k5a, uint32_t k5b, uint32_t k6a, uint32_t k6b,
    uint32_t k7a, uint32_t k7b, uint32_t k8a, uint32_t k8b,
    uint32_t k9a, uint32_t k9b, int do_meas) {
  uint32_t tid = blockIdx.x * 256 + threadIdx.x;  // < 1048576 (pair, col)
  uint32_t i = tid >> 9, c = tid & 511u;
  int i1 = pidx[2 * i], i2 = pidx[2 * i + 1];
  float p1 = pop[(size_t)i1 * 512 + c];
  float p2 = pop[(size_t)i2 * 512 + c];
  float ucm = u01f(randbits32(k3a, k3b, tid));
  float uef = u01f(randbits32(k4a, k4b, tid));
  bool cm = ucm < 0.5f;
  float c1 = cm ? p1 : p2;
  float c2 = cm ? p2 : p1;
  float ef = uef * 0.2f;
  float mean = (p1 + p2) * 0.5f;
  float t = ef * mean;
  c1 = c1 + t;
  c2 = c2 + t;
  uint32_t e1 = (2 * i) * 512 + c;
  uint32_t e2 = e1 + 512;
  c1 = mutate_val(c1, e1, k5a, k5b, k6a, k6b, k7a, k7b, k8a, k8b, k9a, k9b, do_meas);
  c2 = mutate_val(c2, e2, k5a, k5b, k6a, k6b, k7a, k7b, k8a, k8b, k9a, k9b, do_meas);
  out[e1] = c1;
  out[e2] = c2;
}

// ---------------- final: best row + max fit + objective weights -------------
__global__ __launch_bounds__(1024) void final_kernel(
    const float* __restrict__ fit, const float* __restrict__ pop,
    const float* __restrict__ objw, float* __restrict__ out) {
  __shared__ float vs[1024];
  __shared__ int isi[1024];
  int t = threadIdx.x;
  float bv = -3.4e38f; int bi = 0x7fffffff;
  for (int i = t; i < POP; i += 1024) {
    float v = fit[i];
    if (v > bv) { bv = v; bi = i; }
  }
  vs[t] = bv; isi[t] = bi; __syncthreads();
  for (int h = 512; h > 0; h >>= 1) {
    if (t < h) {
      float v2 = vs[t + h]; int j2 = isi[t + h];
      if (v2 > vs[t] || (v2 == vs[t] && j2 < isi[t])) { vs[t] = v2; isi[t] = j2; }
    }
    __syncthreads();
  }
  int gbi = isi[0]; float gbv = vs[0];
  if (t < 512) out[t] = pop[(size_t)gbi * 512 + t];
  if (t == 0) out[512] = gbv;
  if (t >= 513 && t < 518) out[t] = objw[t - 513];
}

// ---------------- host orchestration ----------------
extern "C" void kernel_launch(void* const* d_in, const int* in_sizes, int n_in,
                              void* d_out, int out_size, void* d_ws, size_t ws_size,
                              hipStream_t stream) {
  const float* pctx  = (const float*)d_in[0];
  const float* qkvw  = (const float*)d_in[1];
  const float* qkvb  = (const float*)d_in[2];
  const float* outw  = (const float*)d_in[3];
  const float* outb  = (const float*)d_in[4];
  const float* ff1w  = (const float*)d_in[5];
  const float* ff1b  = (const float*)d_in[6];
  const float* ff2w  = (const float*)d_in[7];
  const float* ff2b  = (const float*)d_in[8];
  const float* ln1w  = (const float*)d_in[9];
  const float* ln1b  = (const float*)d_in[10];
  const float* ln2w  = (const float*)d_in[11];
  const float* ln2b  = (const float*)d_in[12];
  const float* fw1   = (const float*)d_in[13];
  const float* fb1   = (const float*)d_in[14];
  const float* fw2   = (const float*)d_in[15];
  const float* fb2   = (const float*)d_in[16];
  const float* fw3   = (const float*)d_in[17];
  const float* fb3   = (const float*)d_in[18];
  const float* entraw= (const float*)d_in[19];
  const float* objw  = (const float*)d_in[20];
  float* out = (float*)d_out;

  // workspace layout (floats)
  float* ws    = (float*)d_ws;
  float* popA  = ws;                    // 2097152
  float* popB  = popA + 2097152;        // 2097152
  float* qe    = popB + 2097152;        // 2097152
  float* h1    = qe + 2097152;          // 1048576
  float* h2    = h1 + 1048576;          // 524288
  float* fitb  = h2 + 524288;           // 4096
  float* encx  = fitb + 4096;           // 512
  float* enct1 = encx + 512;            // 2048
  float* enct2 = enct1 + 2048;          // 512
  float* rowm  = enct2 + 512;           // 4096
  float* rowsum= rowm + 4096;           // 4096
  int*   pidx  = (int*)(rowsum + 4096); // 4096 ints
  float* ent   = (float*)(pidx + 4096); // 16777216 (optional)
  size_t base_floats = (size_t)(2097152 * 3 + 1048576 + 524288 + 4096 + 512 + 2048 + 512 + 4096 + 4096 + 4096);
  size_t need_small = base_floats * 4;
  size_t need_big = (base_floats + 16777216) * 4;
  if (ws_size < need_small) return;  // cannot run; fails loudly
  const bool materialize = (ws_size >= need_big);

  // ---- encoder (S=1: attention output == V) ----
  hipMemcpyAsync(encx, pctx, 512 * sizeof(float), hipMemcpyDeviceToDevice, stream);
  for (int l = 0; l < 6; l++) {
    matvec_kernel<<<128, 256, 0, stream>>>(qkvw + ((size_t)l * 1536 + 1024) * 512,
                                           qkvb + (size_t)l * 1536 + 1024, encx, enct1, 512, 512, 0);
    matvec_kernel<<<128, 256, 0, stream>>>(outw + (size_t)l * 512 * 512,
                                           outb + (size_t)l * 512, enct1, enct2, 512, 512, 0);
    ln_kernel<<<1, 512, 0, stream>>>(encx, enct2, ln1w + l * 512, ln1b + l * 512);
    matvec_kernel<<<512, 256, 0, stream>>>(ff1w + (size_t)l * 2048 * 512,
                                           ff1b + (size_t)l * 2048, encx, enct1, 2048, 512, 1);
    matvec_kernel<<<128, 256, 0, stream>>>(ff2w + (size_t)l * 512 * 2048,
                                           ff2b + (size_t)l * 512, enct1, enct2, 512, 2048, 0);
    ln_kernel<<<1, 512, 0, stream>>>(encx, enct2, ln2w + l * 512, ln2b + l * 512);
  }

  // ---- entanglement softmax stats (+ optional materialization) ----
  rowstats_kernel<<<4096, 256, 0, stream>>>(entraw, rowm, rowsum);
  if (materialize)
    softmax_write_kernel<<<4096, 256, 0, stream>>>(entraw, rowm, rowsum, ent);

  // ---- pop0: normal(fold_in(key(42), 0), (POP,D)) + ctx*0.1 ----
  uint32_t kp0, kp1; tf2x32(0u, 42u, 0u, 0u, kp0, kp1);  // fold_in(key, 0)
  pop0_kernel<<<8192, 256, 0, stream>>>(popA, encx, kp0, kp1);

  // ---- generations ----
  float* cur = popA; float* nxt = popB;
  for (int g = 0; g < GENS; ++g) {
    uint32_t kg0, kg1; tf2x32(0u, 42u, 0u, (uint32_t)(g + 1), kg0, kg1);  // fold_in
    // partitionable (foldlike) split(k, 10): ks[i] = threefry(k, (0, i))
    uint32_t ks[10][2];
    for (int i = 0; i < 10; i++) tf2x32(kg0, kg1, 0u, (uint32_t)i, ks[i][0], ks[i][1]);
    // randint's internal split(ks[1], 2) [foldlike]: k2 = threefry(ks[1], (0, 1))
    uint32_t ki0, ki1; tf2x32(ks[1][0], ks[1][1], 0u, 1u, ki0, ki1);

    if (materialize)
      gemm_ent_kernel<0><<<dim3(8, 64), 256, 0, stream>>>(ent, rowm, rowsum, cur, encx, qe);
    else
      gemm_ent_kernel<1><<<dim3(8, 64), 256, 0, stream>>>(entraw, rowm, rowsum, cur, encx, qe);
    gemm_fc_kernel<1><<<dim3(4, 64), 256, 0, stream>>>(qe, fw1, fb1, h1, 256, 512);
    gemm_fc_kernel<1><<<dim3(2, 64), 256, 0, stream>>>(h1, fw2, fb2, h2, 128, 256);
    fit_kernel<<<1024, 256, 0, stream>>>(h2, fw3, fb3, fitb, ks[0][0], ks[0][1]);
    select_kernel<<<16, 256, 0, stream>>>(fitb, pidx, ki0, ki1, ks[2][0], ks[2][1]);
    offspring_kernel<<<4096, 256, 0, stream>>>(cur, pidx, nxt,
        ks[3][0], ks[3][1], ks[4][0], ks[4][1], ks[5][0], ks[5][1], ks[6][0], ks[6][1],
        ks[7][0], ks[7][1], ks[8][0], ks[8][1], ks[9][0], ks[9][1], (g % 10 == 0) ? 1 : 0);
    float* tswap = cur; cur = nxt; nxt = tswap;
  }

  final_kernel<<<1, 1024, 0, stream>>>(fitb, cur, objw, out);
}

// Round 9
// 16854.774 us; speedup vs baseline: 1.0775x; 1.0113x over previous
//
#include <hip/hip_runtime.h>
#include <stdint.h>

#pragma clang fp contract(off)

#define POP 4096
#define DIM 512
#define GENS 50

// ---------------- threefry2x32 (JAX-compatible) ----------------
__host__ __device__ __forceinline__ void tf2x32(uint32_t k0, uint32_t k1,
                                                uint32_t x0, uint32_t x1,
                                                uint32_t &o0, uint32_t &o1) {
  uint32_t ks2 = k0 ^ k1 ^ 0x1BD11BDAu;
#define TFR(r) do { x0 += x1; x1 = (x1 << (r)) | (x1 >> (32 - (r))); x1 ^= x0; } while (0)
  x0 += k0; x1 += k1;
  TFR(13); TFR(15); TFR(26); TFR(6);
  x0 += k1; x1 += ks2 + 1u;
  TFR(17); TFR(29); TFR(16); TFR(24);
  x0 += ks2; x1 += k0 + 2u;
  TFR(13); TFR(15); TFR(26); TFR(6);
  x0 += k0; x1 += k1 + 3u;
  TFR(17); TFR(29); TFR(16); TFR(24);
  x0 += k1; x1 += ks2 + 4u;
  TFR(13); TFR(15); TFR(26); TFR(6);
  x0 += ks2; x1 += k0 + 5u;
#undef TFR
  o0 = x0; o1 = x1;
}

// JAX partitionable threefry (default in modern JAX):
// random_bits(key, 32, shape)[i] = o0 ^ o1 of threefry2x32(key, (0, i))
__device__ __forceinline__ uint32_t randbits32(uint32_t k0, uint32_t k1, uint32_t e) {
  uint32_t y0, y1;
  tf2x32(k0, k1, 0u, e, y0, y1);
  return y0 ^ y1;
}

__device__ __forceinline__ float u01f(uint32_t bits) {
  return __uint_as_float((bits >> 9) | 0x3F800000u) - 1.0f;
}

// XLA f32 erfinv (Giles) — separate mul+add (no contraction), matching XLA IR
__device__ __forceinline__ float erfinv32(float x) {
  float w = -log1pf(-x * x);
  float p;
  if (w < 5.0f) {
    w = w - 2.5f;
    p = 2.81022636e-08f;
    p = p * w + 3.43273939e-07f;
    p = p * w + -3.5233877e-06f;
    p = p * w + -4.39150654e-06f;
    p = p * w + 0.00021858087f;
    p = p * w + -0.00125372503f;
    p = p * w + -0.00417768164f;
    p = p * w + 0.246640727f;
    p = p * w + 1.50140941f;
  } else {
    w = sqrtf(w) - 3.0f;
    p = -0.000200214257f;
    p = p * w + 0.000100950558f;
    p = p * w + 0.00134934322f;
    p = p * w + -0.00367342844f;
    p = p * w + 0.00573950773f;
    p = p * w + -0.0076224613f;
    p = p * w + 0.00943887047f;
    p = p * w + 1.00167406f;
    p = p * w + 2.83297682f;
  }
  return p * x;
}

// jax.random.normal element: u = f*2.0f + lo (lo = -(1-2^-24)), sqrt2*erfinv
__device__ __forceinline__ float normal_elem(uint32_t k0, uint32_t k1, uint32_t e) {
  float f = u01f(randbits32(k0, k1, e));
  float u = f * 2.0f + (-0.99999994039535522f);
  u = fmaxf(-0.99999994039535522f, u);
  return 1.41421353816986084f * erfinv32(u);  // float(np.sqrt(2))
}

// ---------------- encoder: matvec out[j] = act(bias[j] + dot(W[j,:], x)) ----
__global__ __launch_bounds__(256) void matvec_kernel(
    const float* __restrict__ W, const float* __restrict__ bias,
    const float* __restrict__ x, float* __restrict__ out,
    int N, int K, int act) {
  int j = (blockIdx.x * blockDim.x + threadIdx.x) >> 6;
  int lane = threadIdx.x & 63;
  if (j >= N) return;
  const float* wr = W + (size_t)j * K;
  float acc = 0.0f;
  for (int k = lane; k < K; k += 64) acc = fmaf(wr[k], x[k], acc);
#pragma unroll
  for (int o = 32; o > 0; o >>= 1) acc += __shfl_down(acc, o, 64);
  if (lane == 0) {
    float v = acc + bias[j];
    if (act) v = fmaxf(v, 0.0f);
    out[j] = v;
  }
}

// layernorm in-place: x = LN(x + delta) * w + b
__global__ __launch_bounds__(512) void ln_kernel(
    float* __restrict__ x, const float* __restrict__ delta,
    const float* __restrict__ w, const float* __restrict__ b) {
  __shared__ float s[512];
  int t = threadIdx.x;
  float v = x[t] + delta[t];
  s[t] = v; __syncthreads();
  for (int h = 256; h > 0; h >>= 1) { if (t < h) s[t] += s[t + h]; __syncthreads(); }
  float m = s[0] * (1.0f / 512.0f);
  __syncthreads();
  float d = v - m;
  s[t] = d * d; __syncthreads();
  for (int h = 256; h > 0; h >>= 1) { if (t < h) s[t] += s[t + h]; __syncthreads(); }
  float var = s[0] * (1.0f / 512.0f);
  float o = d / sqrtf(var + 1e-5f) * w[t] + b[t];
  x[t] = o;
}

// ---------------- row softmax stats (max, sum of exp) -----------------------
__global__ __launch_bounds__(256) void rowstats_kernel(const float* __restrict__ in,
                                                       float* __restrict__ rowm,
                                                       float* __restrict__ rowsum) {
  __shared__ float red[4];
  int r = blockIdx.x;
  const float* row = in + (size_t)r * 4096;
  int t = threadIdx.x, lane = t & 63, wid = t >> 6;
  float v[16];
#pragma unroll
  for (int q = 0; q < 4; q++) {
    float4 f = *reinterpret_cast<const float4*>(row + (size_t)(t + 256 * q) * 4);
    v[q * 4 + 0] = f.x; v[q * 4 + 1] = f.y; v[q * 4 + 2] = f.z; v[q * 4 + 3] = f.w;
  }
  float m = v[0];
#pragma unroll
  for (int q = 1; q < 16; q++) m = fmaxf(m, v[q]);
#pragma unroll
  for (int o = 32; o > 0; o >>= 1) m = fmaxf(m, __shfl_xor(m, o, 64));
  if (lane == 0) red[wid] = m;
  __syncthreads();
  float bm = fmaxf(fmaxf(red[0], red[1]), fmaxf(red[2], red[3]));
  __syncthreads();
  float sum = 0.0f;
#pragma unroll
  for (int q = 0; q < 16; q++) sum += expf(v[q] - bm);
#pragma unroll
  for (int o = 32; o > 0; o >>= 1) sum += __shfl_xor(sum, o, 64);
  if (lane == 0) red[wid] = sum;
  __syncthreads();
  if (t == 0) {
    rowm[r] = bm;
    rowsum[r] = (red[0] + red[1]) + (red[2] + red[3]);
  }
}

// ---------------- full softmax materialization (if ws allows) ---------------
__global__ __launch_bounds__(256) void softmax_write_kernel(
    const float* __restrict__ in, const float* __restrict__ rowm,
    const float* __restrict__ rowsum, float* __restrict__ out) {
  int r = blockIdx.x;
  float bm = rowm[r], bs = rowsum[r];
  const float* row = in + (size_t)r * 4096;
  float* orow = out + (size_t)r * 4096;
  int t = threadIdx.x;
#pragma unroll
  for (int q = 0; q < 4; q++) {
    float4 f = *reinterpret_cast<const float4*>(row + (size_t)(t + 256 * q) * 4);
    f.x = expf(f.x - bm) / bs; f.y = expf(f.y - bm) / bs;
    f.z = expf(f.z - bm) / bs; f.w = expf(f.w - bm) / bs;
    *reinterpret_cast<float4*>(orow + (size_t)(t + 256 * q) * 4) = f;
  }
}

// ---------------- pop0 ----------------
__global__ __launch_bounds__(256) void pop0_kernel(float* __restrict__ pop,
                                                   const float* __restrict__ ctx,
                                                   uint32_t k0, uint32_t k1) {
  uint32_t e = blockIdx.x * 256 + threadIdx.x;
  float n = normal_elem(k0, k1, e);
  int c = e & 511u;
  float t = ctx[c] * 0.1f;
  pop[e] = n + t;
}

// ---- ent GEMM: qe = (pop+ctx) + 0.3*(softmax(raw) @ (pop+ctx)) -------------
// VERIFIED round-7 kernel body (256 threads, 64x64 tile, 4x4 acc, transposed
// A in LDS). Single change: 1D grid decoded by=bid&63 so the 8 col-blocks of
// an A-stripe satisfy bid%8 == by%8 -> same XCD -> A re-reads are L2 hits.
// Work per (bx,by) identical and bijective => bit-identical output.
template <int ONFLY>
__global__ __launch_bounds__(256) void gemm_ent_kernel(
    const float* __restrict__ A, const float* __restrict__ rowm,
    const float* __restrict__ rowsum, const float* __restrict__ pop,
    const float* __restrict__ ctx, float* __restrict__ qe) {
  __shared__ __align__(16) float As[32][68];  // [k][m] transposed, +pad
  __shared__ __align__(16) float Bs[32][68];  // [k][n]
  const int t = threadIdx.x;
  const int tx = t & 15, ty = t >> 4;
  const int bid = blockIdx.x;
  const int bx = bid >> 6;                     // col-tile 0..7
  const int by = bid & 63;                     // row-tile 0..63
  const int row0 = by * 64, col0 = bx * 64;
  const int am0 = t >> 3, akq = t & 7;
  const int bkk = t >> 4, bnq = t & 15;
  float4 cvec = *reinterpret_cast<const float4*>(ctx + col0 + bnq * 4);
  float mr[2], sr[2];
  if (ONFLY) {
#pragma unroll
    for (int s = 0; s < 2; s++) {
      int r = row0 + am0 + s * 32;
      mr[s] = rowm[r]; sr[s] = rowsum[r];
    }
  }
  float acc[4][4] = {{0.f}};
  for (int kt = 0; kt < 4096; kt += 32) {
#pragma unroll
    for (int s = 0; s < 2; s++) {
      int m = am0 + s * 32;
      float4 a4 = *reinterpret_cast<const float4*>(A + (size_t)(row0 + m) * 4096 + kt + akq * 4);
      if (ONFLY) {
        a4.x = expf(a4.x - mr[s]) / sr[s];
        a4.y = expf(a4.y - mr[s]) / sr[s];
        a4.z = expf(a4.z - mr[s]) / sr[s];
        a4.w = expf(a4.w - mr[s]) / sr[s];
      }
      As[akq * 4 + 0][m] = a4.x; As[akq * 4 + 1][m] = a4.y;
      As[akq * 4 + 2][m] = a4.z; As[akq * 4 + 3][m] = a4.w;
    }
#pragma unroll
    for (int s = 0; s < 2; s++) {
      int kk = bkk + s * 16;
      float4 b4 = *reinterpret_cast<const float4*>(pop + (size_t)(kt + kk) * 512 + col0 + bnq * 4);
      b4.x += cvec.x; b4.y += cvec.y; b4.z += cvec.z; b4.w += cvec.w;
      *reinterpret_cast<float4*>(&Bs[kk][bnq * 4]) = b4;
    }
    __syncthreads();
#pragma unroll
    for (int k = 0; k < 32; k++) {
      float4 a = *reinterpret_cast<const float4*>(&As[k][ty * 4]);
      float4 b = *reinterpret_cast<const float4*>(&Bs[k][tx * 4]);
      acc[0][0] = fmaf(a.x, b.x, acc[0][0]);
      acc[0][1] = fmaf(a.x, b.y, acc[0][1]);
      acc[0][2] = fmaf(a.x, b.z, acc[0][2]);
      acc[0][3] = fmaf(a.x, b.w, acc[0][3]);
      acc[1][0] = fmaf(a.y, b.x, acc[1][0]);
      acc[1][1] = fmaf(a.y, b.y, acc[1][1]);
      acc[1][2] = fmaf(a.y, b.z, acc[1][2]);
      acc[1][3] = fmaf(a.y, b.w, acc[1][3]);
      acc[2][0] = fmaf(a.z, b.x, acc[2][0]);
      acc[2][1] = fmaf(a.z, b.y, acc[2][1]);
      acc[2][2] = fmaf(a.z, b.z, acc[2][2]);
      acc[2][3] = fmaf(a.z, b.w, acc[2][3]);
      acc[3][0] = fmaf(a.w, b.x, acc[3][0]);
      acc[3][1] = fmaf(a.w, b.y, acc[3][1]);
      acc[3][2] = fmaf(a.w, b.z, acc[3][2]);
      acc[3][3] = fmaf(a.w, b.w, acc[3][3]);
    }
    __syncthreads();
  }
#pragma unroll
  for (int ii = 0; ii < 4; ii++) {
    int r = row0 + ty * 4 + ii;
    float4 p4 = *reinterpret_cast<const float4*>(pop + (size_t)r * 512 + col0 + tx * 4);
    float4 cx = *reinterpret_cast<const float4*>(ctx + col0 + tx * 4);
    float4 o;
    o.x = (p4.x + cx.x) + 0.3f * acc[ii][0];
    o.y = (p4.y + cx.y) + 0.3f * acc[ii][1];
    o.z = (p4.z + cx.z) + 0.3f * acc[ii][2];
    o.w = (p4.w + cx.w) + 0.3f * acc[ii][3];
    *reinterpret_cast<float4*>(qe + (size_t)r * 512 + col0 + tx * 4) = o;
  }
}

// ---------------- fc GEMM: out = act(A @ W.T + bias), W row-major [N][K] ----
// (unchanged from verified round-7 kernel)
template <int ACT>
__global__ __launch_bounds__(256) void gemm_fc_kernel(
    const float* __restrict__ A, const float* __restrict__ W,
    const float* __restrict__ bias, float* __restrict__ out, int N, int K) {
  __shared__ __align__(16) float As[32][68];  // [k][m]
  __shared__ __align__(16) float Ws[32][68];  // [k][n]
  const int t = threadIdx.x;
  const int tx = t & 15, ty = t >> 4;
  const int row0 = blockIdx.y * 64, col0 = blockIdx.x * 64;
  const int m0 = t >> 3, kq = t & 7;
  float acc[4][4] = {{0.f}};
  for (int kt = 0; kt < K; kt += 32) {
#pragma unroll
    for (int s = 0; s < 2; s++) {
      int m = m0 + s * 32;
      float4 a4 = *reinterpret_cast<const float4*>(A + (size_t)(row0 + m) * K + kt + kq * 4);
      As[kq * 4 + 0][m] = a4.x; As[kq * 4 + 1][m] = a4.y;
      As[kq * 4 + 2][m] = a4.z; As[kq * 4 + 3][m] = a4.w;
      float4 w4 = *reinterpret_cast<const float4*>(W + (size_t)(col0 + m) * K + kt + kq * 4);
      Ws[kq * 4 + 0][m] = w4.x; Ws[kq * 4 + 1][m] = w4.y;
      Ws[kq * 4 + 2][m] = w4.z; Ws[kq * 4 + 3][m] = w4.w;
    }
    __syncthreads();
#pragma unroll
    for (int k = 0; k < 32; k++) {
      float4 a = *reinterpret_cast<const float4*>(&As[k][ty * 4]);
      float4 b = *reinterpret_cast<const float4*>(&Ws[k][tx * 4]);
      acc[0][0] = fmaf(a.x, b.x, acc[0][0]);
      acc[0][1] = fmaf(a.x, b.y, acc[0][1]);
      acc[0][2] = fmaf(a.x, b.z, acc[0][2]);
      acc[0][3] = fmaf(a.x, b.w, acc[0][3]);
      acc[1][0] = fmaf(a.y, b.x, acc[1][0]);
      acc[1][1] = fmaf(a.y, b.y, acc[1][1]);
      acc[1][2] = fmaf(a.y, b.z, acc[1][2]);
      acc[1][3] = fmaf(a.y, b.w, acc[1][3]);
      acc[2][0] = fmaf(a.z, b.x, acc[2][0]);
      acc[2][1] = fmaf(a.z, b.y, acc[2][1]);
      acc[2][2] = fmaf(a.z, b.z, acc[2][2]);
      acc[2][3] = fmaf(a.z, b.w, acc[2][3]);
      acc[3][0] = fmaf(a.w, b.x, acc[3][0]);
      acc[3][1] = fmaf(a.w, b.y, acc[3][1]);
      acc[3][2] = fmaf(a.w, b.z, acc[3][2]);
      acc[3][3] = fmaf(a.w, b.w, acc[3][3]);
    }
    __syncthreads();
  }
#pragma unroll
  for (int ii = 0; ii < 4; ii++) {
    int r = row0 + ty * 4 + ii;
    float4 o;
    o.x = acc[ii][0] + bias[col0 + tx * 4 + 0];
    o.y = acc[ii][1] + bias[col0 + tx * 4 + 1];
    o.z = acc[ii][2] + bias[col0 + tx * 4 + 2];
    o.w = acc[ii][3] + bias[col0 + tx * 4 + 3];
    if (ACT) { o.x = fmaxf(o.x, 0.f); o.y = fmaxf(o.y, 0.f); o.z = fmaxf(o.z, 0.f); o.w = fmaxf(o.w, 0.f); }
    *reinterpret_cast<float4*>(out + (size_t)r * N + col0 + tx * 4) = o;
  }
}

// ---------------- fitness: sigmoid(h2 @ w3.T + b3) + 0.1*normal --------------
__global__ __launch_bounds__(256) void fit_kernel(
    const float* __restrict__ h2, const float* __restrict__ w3,
    const float* __restrict__ b3, float* __restrict__ fit,
    uint32_t k0, uint32_t k1) {
  int gid = blockIdx.x * 256 + threadIdx.x;
  int m = gid >> 6, lane = gid & 63;
  if (m >= POP) return;
  const float* r = h2 + (size_t)m * 128;
  float acc = fmaf(r[lane], w3[lane], r[lane + 64] * w3[lane + 64]);
#pragma unroll
  for (int o = 32; o > 0; o >>= 1) acc += __shfl_down(acc, o, 64);
  if (lane == 0) {
    float s = 1.0f / (1.0f + expf(-(acc + b3[0])));
    float n = normal_elem(k0, k1, (uint32_t)m);
    float t = 0.1f * n;
    fit[m] = s + t;
  }
}

// ---------------- tournament + categorical selection ------------------------
__global__ __launch_bounds__(256) void select_kernel(
    const float* __restrict__ fit, int* __restrict__ pidx,
    uint32_t ki0, uint32_t ki1,    // k2 of split(ks[1])
    uint32_t kg0, uint32_t kg1) {  // ks[2] (gumbel)
  int r = blockIdx.x * 256 + threadIdx.x;
  if (r >= POP) return;
  float bestv = 0.f; int bestidx = 0; bool first = true;
#pragma unroll
  for (int t = 0; t < 5; t++) {
    uint32_t i = (uint32_t)(r * 5 + t);
    int idx = (int)(randbits32(ki0, ki1, i) & 4095u);
    float f = u01f(randbits32(kg0, kg1, i));
    float u = (f == 0.0f) ? 1.17549435e-38f : f;  // uniform(tiny, 1)
    float g = -logf(-logf(u));
    float val = g + fit[idx] * 10.0f;
    if (first || val > bestv) { bestv = val; bestidx = idx; first = false; }
  }
  pidx[r] = bestidx;
}

// ---------------- crossover + mutation + tunneling + measurement ------------
__device__ __forceinline__ float mutate_val(
    float v, uint32_t e,
    uint32_t k5a, uint32_t k5b, uint32_t k6a, uint32_t k6b,
    uint32_t k7a, uint32_t k7b, uint32_t k8a, uint32_t k8b,
    uint32_t k9a, uint32_t k9b, int do_meas) {
  float um = u01f(randbits32(k5a, k5b, e));
  if (um < 0.15f) {
    float n = normal_elem(k6a, k6b, e);
    float t = n * 0.1f;
    v = v + t;
  }
  float ut = u01f(randbits32(k7a, k7b, e));
  if (ut < 0.05f) {
    float n = normal_elem(k8a, k8b, e);
    float t = n * 0.5f;
    v = v + t;
  }
  if (do_meas) {
    float n = normal_elem(k9a, k9b, e);
    float t = n * 0.05f;
    v = v + t;
  }
  return v;
}

__global__ __launch_bounds__(256) void offspring_kernel(
    const float* __restrict__ pop, const int* __restrict__ pidx,
    float* __restrict__ out,
    uint32_t k3a, uint32_t k3b, uint32_t k4a, uint32_t k4b,
    uint32_t k5a, uint32_t k5b, uint32_t k6a, uint32_t k6b,
    uint32_t k7a, uint32_t k7b, uint32_t k8a, uint32_t k8b,
    uint32_t k9a, uint32_t k9b, int do_meas) {
  uint32_t tid = blockIdx.x * 256 + threadIdx.x;  // < 1048576 (pair, col)
  uint32_t i = tid >> 9, c = tid & 511u;
  int i1 = pidx[2 * i], i2 = pidx[2 * i + 1];
  float p1 = pop[(size_t)i1 * 512 + c];
  float p2 = pop[(size_t)i2 * 512 + c];
  float ucm = u01f(randbits32(k3a, k3b, tid));
  float uef = u01f(randbits32(k4a, k4b, tid));
  bool cm = ucm < 0.5f;
  float c1 = cm ? p1 : p2;
  float c2 = cm ? p2 : p1;
  float ef = uef * 0.2f;
  float mean = (p1 + p2) * 0.5f;
  float t = ef * mean;
  c1 = c1 + t;
  c2 = c2 + t;
  uint32_t e1 = (2 * i) * 512 + c;
  uint32_t e2 = e1 + 512;
  c1 = mutate_val(c1, e1, k5a, k5b, k6a, k6b, k7a, k7b, k8a, k8b, k9a, k9b, do_meas);
  c2 = mutate_val(c2, e2, k5a, k5b, k6a, k6b, k7a, k7b, k8a, k8b, k9a, k9b, do_meas);
  out[e1] = c1;
  out[e2] = c2;
}

// ---------------- final: best row + max fit + objective weights -------------
__global__ __launch_bounds__(1024) void final_kernel(
    const float* __restrict__ fit, const float* __restrict__ pop,
    const float* __restrict__ objw, float* __restrict__ out) {
  __shared__ float vs[1024];
  __shared__ int isi[1024];
  int t = threadIdx.x;
  float bv = -3.4e38f; int bi = 0x7fffffff;
  for (int i = t; i < POP; i += 1024) {
    float v = fit[i];
    if (v > bv) { bv = v; bi = i; }
  }
  vs[t] = bv; isi[t] = bi; __syncthreads();
  for (int h = 512; h > 0; h >>= 1) {
    if (t < h) {
      float v2 = vs[t + h]; int j2 = isi[t + h];
      if (v2 > vs[t] || (v2 == vs[t] && j2 < isi[t])) { vs[t] = v2; isi[t] = j2; }
    }
    __syncthreads();
  }
  int gbi = isi[0]; float gbv = vs[0];
  if (t < 512) out[t] = pop[(size_t)gbi * 512 + t];
  if (t == 0) out[512] = gbv;
  if (t >= 513 && t < 518) out[t] = objw[t - 513];
}

// ---------------- host orchestration ----------------
extern "C" void kernel_launch(void* const* d_in, const int* in_sizes, int n_in,
                              void* d_out, int out_size, void* d_ws, size_t ws_size,
                              hipStream_t stream) {
  const float* pctx  = (const float*)d_in[0];
  const float* qkvw  = (const float*)d_in[1];
  const float* qkvb  = (const float*)d_in[2];
  const float* outw  = (const float*)d_in[3];
  const float* outb  = (const float*)d_in[4];
  const float* ff1w  = (const float*)d_in[5];
  const float* ff1b  = (const float*)d_in[6];
  const float* ff2w  = (const float*)d_in[7];
  const float* ff2b  = (const float*)d_in[8];
  const float* ln1w  = (const float*)d_in[9];
  const float* ln1b  = (const float*)d_in[10];
  const float* ln2w  = (const float*)d_in[11];
  const float* ln2b  = (const float*)d_in[12];
  const float* fw1   = (const float*)d_in[13];
  const float* fb1   = (const float*)d_in[14];
  const float* fw2   = (const float*)d_in[15];
  const float* fb2   = (const float*)d_in[16];
  const float* fw3   = (const float*)d_in[17];
  const float* fb3   = (const float*)d_in[18];
  const float* entraw= (const float*)d_in[19];
  const float* objw  = (const float*)d_in[20];
  float* out = (float*)d_out;

  // workspace layout (floats)
  float* ws    = (float*)d_ws;
  float* popA  = ws;                    // 2097152
  float* popB  = popA + 2097152;        // 2097152
  float* qe    = popB + 2097152;        // 2097152
  float* h1    = qe + 2097152;          // 1048576
  float* h2    = h1 + 1048576;          // 524288
  float* fitb  = h2 + 524288;           // 4096
  float* encx  = fitb + 4096;           // 512
  float* enct1 = encx + 512;            // 2048
  float* enct2 = enct1 + 2048;          // 512
  float* rowm  = enct2 + 512;           // 4096
  float* rowsum= rowm + 4096;           // 4096
  int*   pidx  = (int*)(rowsum + 4096); // 4096 ints
  float* ent   = (float*)(pidx + 4096); // 16777216 (optional)
  size_t base_floats = (size_t)(2097152 * 3 + 1048576 + 524288 + 4096 + 512 + 2048 + 512 + 4096 + 4096 + 4096);
  size_t need_small = base_floats * 4;
  size_t need_big = (base_floats + 16777216) * 4;
  if (ws_size < need_small) return;  // cannot run; fails loudly
  const bool materialize = (ws_size >= need_big);

  // ---- encoder (S=1: attention output == V) ----
  hipMemcpyAsync(encx, pctx, 512 * sizeof(float), hipMemcpyDeviceToDevice, stream);
  for (int l = 0; l < 6; l++) {
    matvec_kernel<<<128, 256, 0, stream>>>(qkvw + ((size_t)l * 1536 + 1024) * 512,
                                           qkvb + (size_t)l * 1536 + 1024, encx, enct1, 512, 512, 0);
    matvec_kernel<<<128, 256, 0, stream>>>(outw + (size_t)l * 512 * 512,
                                           outb + (size_t)l * 512, enct1, enct2, 512, 512, 0);
    ln_kernel<<<1, 512, 0, stream>>>(encx, enct2, ln1w + l * 512, ln1b + l * 512);
    matvec_kernel<<<512, 256, 0, stream>>>(ff1w + (size_t)l * 2048 * 512,
                                           ff1b + (size_t)l * 2048, encx, enct1, 2048, 512, 1);
    matvec_kernel<<<128, 256, 0, stream>>>(ff2w + (size_t)l * 512 * 2048,
                                           ff2b + (size_t)l * 512, enct1, enct2, 512, 2048, 0);
    ln_kernel<<<1, 512, 0, stream>>>(encx, enct2, ln2w + l * 512, ln2b + l * 512);
  }

  // ---- entanglement softmax stats (+ optional materialization) ----
  rowstats_kernel<<<4096, 256, 0, stream>>>(entraw, rowm, rowsum);
  if (materialize)
    softmax_write_kernel<<<4096, 256, 0, stream>>>(entraw, rowm, rowsum, ent);

  // ---- pop0: normal(fold_in(key(42), 0), (POP,D)) + ctx*0.1 ----
  uint32_t kp0, kp1; tf2x32(0u, 42u, 0u, 0u, kp0, kp1);  // fold_in(key, 0)
  pop0_kernel<<<8192, 256, 0, stream>>>(popA, encx, kp0, kp1);

  // ---- generations ----
  float* cur = popA; float* nxt = popB;
  for (int g = 0; g < GENS; ++g) {
    uint32_t kg0, kg1; tf2x32(0u, 42u, 0u, (uint32_t)(g + 1), kg0, kg1);  // fold_in
    // partitionable (foldlike) split(k, 10): ks[i] = threefry(k, (0, i))
    uint32_t ks[10][2];
    for (int i = 0; i < 10; i++) tf2x32(kg0, kg1, 0u, (uint32_t)i, ks[i][0], ks[i][1]);
    // randint's internal split(ks[1], 2) [foldlike]: k2 = threefry(ks[1], (0, 1))
    uint32_t ki0, ki1; tf2x32(ks[1][0], ks[1][1], 0u, 1u, ki0, ki1);

    if (materialize)
      gemm_ent_kernel<0><<<512, 256, 0, stream>>>(ent, rowm, rowsum, cur, encx, qe);
    else
      gemm_ent_kernel<1><<<512, 256, 0, stream>>>(entraw, rowm, rowsum, cur, encx, qe);
    gemm_fc_kernel<1><<<dim3(4, 64), 256, 0, stream>>>(qe, fw1, fb1, h1, 256, 512);
    gemm_fc_kernel<1><<<dim3(2, 64), 256, 0, stream>>>(h1, fw2, fb2, h2, 128, 256);
    fit_kernel<<<1024, 256, 0, stream>>>(h2, fw3, fb3, fitb, ks[0][0], ks[0][1]);
    select_kernel<<<16, 256, 0, stream>>>(fitb, pidx, ki0, ki1, ks[2][0], ks[2][1]);
    offspring_kernel<<<4096, 256, 0, stream>>>(cur, pidx, nxt,
        ks[3][0], ks[3][1], ks[4][0], ks[4][1], ks[5][0], ks[5][1], ks[6][0], ks[6][1],
        ks[7][0], ks[7][1], ks[8][0], ks[8][1], ks[9][0], ks[9][1], (g % 10 == 0) ? 1 : 0);
    float* tswap = cur; cur = nxt; nxt = tswap;
  }

  final_kernel<<<1, 1024, 0, stream>>>(fitb, cur, objw, out);
}